// Round 5
// baseline (113.853 us; speedup 1.0000x reference)
//
#include <hip/hip_runtime.h>
#include <hip/hip_bf16.h>

#define N_CLS 4096
#define FDIM  2048
#define NT    (FDIM / 32)   // 64 K-tiles of BK=32

typedef float  floatx4 __attribute__((ext_vector_type(4)));
typedef short  shortx8 __attribute__((ext_vector_type(8)));

__device__ __forceinline__ unsigned short f2bf(float x) {
    union { float f; unsigned int u; } v; v.f = x;
    unsigned int r = v.u + 0x7fffu + ((v.u >> 16) & 1u);
    return (unsigned short)(r >> 16);
}

// ---------------------------------------------------------------------------
// Kernel 0: zero the accumulator.
// ---------------------------------------------------------------------------
__global__ void zero_kernel(float* __restrict__ accum) { *accum = 0.0f; }

// ---------------------------------------------------------------------------
// Kernel A: per-row norm of prototypes, fp32 diag <p_i, w_i>, bf16 conversion
// of normalized prototypes and classifier weights into workspace.
// ---------------------------------------------------------------------------
__global__ __launch_bounds__(256) void prep_kernel(
    const float* __restrict__ bnd,
    const float* __restrict__ proto,
    const float* __restrict__ wgt,
    unsigned short* __restrict__ pbf,
    unsigned short* __restrict__ wbf,
    float* __restrict__ t1,
    float* __restrict__ cc)
{
    const int row = blockIdx.x;
    const int tid = threadIdx.x;
    const size_t base = (size_t)row * FDIM + (size_t)tid * 8;

    floatx4 p0 = *(const floatx4*)(proto + base);
    floatx4 p1 = *(const floatx4*)(proto + base + 4);
    floatx4 w0 = *(const floatx4*)(wgt + base);
    floatx4 w1 = *(const floatx4*)(wgt + base + 4);

    float ss = 0.f, dt = 0.f;
#pragma unroll
    for (int k = 0; k < 4; ++k) {
        ss += p0[k] * p0[k] + p1[k] * p1[k];
        dt += p0[k] * w0[k] + p1[k] * w1[k];
    }
#pragma unroll
    for (int off = 32; off > 0; off >>= 1) {
        ss += __shfl_down(ss, off);
        dt += __shfl_down(dt, off);
    }

    __shared__ float sss[4], sdt[4];
    __shared__ float srn;
    const int wid = tid >> 6, lane = tid & 63;
    if (lane == 0) { sss[wid] = ss; sdt[wid] = dt; }
    __syncthreads();
    if (tid == 0) {
        float SS = sss[0] + sss[1] + sss[2] + sss[3];
        float DT = sdt[0] + sdt[1] + sdt[2] + sdt[3];
        float rn = 1.0f / fmaxf(sqrtf(SS), 1e-12f);
        srn = rn;
        float bv = bnd[row];
        t1[row] = (1.0f - bv) * (DT * rn);  // (1-b_i) * diag_i  (fp32)
        cc[row] = bv - 1.0f;                // (b_j - 1)
    }
    __syncthreads();
    const float rn = srn;

    shortx8 pv, wv;
#pragma unroll
    for (int k = 0; k < 4; ++k) {
        pv[k]     = (short)f2bf(p0[k] * rn);
        pv[k + 4] = (short)f2bf(p1[k] * rn);
        wv[k]     = (short)f2bf(w0[k]);
        wv[k + 4] = (short)f2bf(w1[k]);
    }
    *(shortx8*)(pbf + base) = pv;
    *(shortx8*)(wbf + base) = wv;
}

// ---------------------------------------------------------------------------
// Kernel B: fused bf16 GEMM (s = P @ W^T) + relu(t1[i] + s*c[j]) off-diag sum.
// BM=BN=256, BK=32, 8 waves (2M x 4N), per-wave output 128x64 (8x4 frags of
// 16x16, acc = 128 VGPR -> 2.67 MFMA per ds_read_b128: MFMA-bound balance).
// 3 LDS buffers (32 KB each, 96 KB total), prefetch distance 2, counted
// vmcnt(4) at tile end (never drained mid-loop). st_16x32-style XOR swizzle
// applied both-sides: pre-swizzled global src (linear global_load_lds dest)
// + swizzled ds_read col. Verified conflict-free (round-4: BANK_CONFLICT=0).
//
// LDS buffer layout (shorts): A [256 rows][32 cols] at 0, B likewise at 8192.
// Swizzle: element col ^= ((row>>3)&1)<<4.
// ---------------------------------------------------------------------------
__global__ __launch_bounds__(512, 2) void gemm_reduce_kernel(
    const unsigned short* __restrict__ A,   // p_bf16 [4096][2048]
    const unsigned short* __restrict__ B,   // w_bf16 [4096][2048]
    const float* __restrict__ t1,
    const float* __restrict__ cc,
    float* __restrict__ accum)
{
    __shared__ unsigned short sAB[3][16384];   // 3 x (8192 A + 8192 B) shorts
    __shared__ float red[8];

    const int tid  = threadIdx.x;
    const int wid  = tid >> 6;
    const int lane = tid & 63;

    // XCD-aware bijective swizzle: 256 blocks -> each XCD owns a 4x8 region
    // of the 16x16 tile grid.
    const int b   = blockIdx.x;
    const int xcd = b & 7, sl = b >> 3;              // sl in 0..31
    const int bi  = ((xcd & 3) << 2) + (sl & 3);     // 0..15
    const int bj  = ((xcd >> 2) << 3) + (sl >> 2);   // 0..15
    const int arow0 = bi * 256;
    const int brow0 = bj * 256;

    const int wm = wid >> 2;   // 0..1 : wave's 128-row strip of A
    const int wn = wid & 3;    // 0..3 : wave's 64-col strip of B
    const int lr = lane & 15;
    // swizzled k-offset (elements) for frag ds_reads:
    const int lkk = ((lane >> 4) << 3) ^ (((lane >> 3) & 1) << 4);

    // staging geometry: chunk = 8 KB = 128 rows x 32 cols, all 512 threads,
    // 1 x 16B load each. Thread t -> LDS row t>>2, col (t&3)*8 (linear);
    // global col pre-swizzled so LDS[row][e] = G[row][e ^ ((row>>3)&1)<<4].
    const int srow  = tid >> 2;                                    // 0..127
    const int sgcol = ((tid & 3) << 3) ^ (((tid >> 5) & 1) << 4);
    const int ldsbase = ((tid >> 2) << 5) & ~511;  // = wid*512, wave-uniform

    floatx4 acc[8][4];
#pragma unroll
    for (int m = 0; m < 8; ++m)
#pragma unroll
        for (int n = 0; n < 4; ++n) acc[m][n] = (floatx4)0.0f;

    // stage chunk j (0,1 = A halves; 2,3 = B halves) of K-tile tt into buf bnx
    auto stage = [&](int j, int tt, int bnx) {
        const int ktt = tt << 5;
        const unsigned short* src = (j < 2)
            ? A + (size_t)(arow0 + ((j & 1) << 7) + srow) * FDIM + ktt + sgcol
            : B + (size_t)(brow0 + ((j & 1) << 7) + srow) * FDIM + ktt + sgcol;
        __builtin_amdgcn_global_load_lds(
            (const __attribute__((address_space(1))) void*)src,
            (__attribute__((address_space(3))) void*)&sAB[bnx][(j << 12) + (wid << 9)],
            16, 0, 0);
    };

    // ---- prologue: stage tiles 0 and 1; wait tile 0 (tile 1 in flight)
#pragma unroll
    for (int j = 0; j < 4; ++j) stage(j, 0, 0);
#pragma unroll
    for (int j = 0; j < 4; ++j) stage(j, 1, 1);
    asm volatile("s_waitcnt vmcnt(4)" ::: "memory");
    __builtin_amdgcn_s_barrier();
    __builtin_amdgcn_sched_barrier(0);

    int cur = 0;
#pragma unroll 1
    for (int t = 0; t < NT; ++t) {
        const int nxt2 = (cur + 2 >= 3) ? cur - 1 : cur + 2;   // (cur+2)%3
        const unsigned short* LA = &sAB[cur][0];
        const unsigned short* LB = &sAB[cur][8192];
        const bool pf = (t + 2 < NT);

        // ---------- sub-phase 0 : C-frags m=0..3 x n=0..3 ----------
        if (pf) { stage(0, t + 2, nxt2); stage(1, t + 2, nxt2); }
        shortx8 af0[4], bf[4];
#pragma unroll
        for (int mi = 0; mi < 4; ++mi)
            af0[mi] = *(const shortx8*)
                &LA[(wm * 128 + mi * 16 + lr) * 32 + lkk];
#pragma unroll
        for (int n = 0; n < 4; ++n)
            bf[n] = *(const shortx8*)
                &LB[(wn * 64 + n * 16 + lr) * 32 + lkk];
        __builtin_amdgcn_s_barrier();
        __builtin_amdgcn_s_setprio(1);
#pragma unroll
        for (int mi = 0; mi < 4; ++mi)
#pragma unroll
            for (int n = 0; n < 4; ++n)
                acc[mi][n] = __builtin_amdgcn_mfma_f32_16x16x32_bf16(
                    af0[mi], bf[n], acc[mi][n], 0, 0, 0);
        __builtin_amdgcn_s_setprio(0);
        __builtin_amdgcn_s_barrier();

        // ---------- sub-phase 1 : C-frags m=4..7 (B frags reused) ----------
        if (pf) { stage(2, t + 2, nxt2); stage(3, t + 2, nxt2); }
        shortx8 af1[4];
#pragma unroll
        for (int mi = 0; mi < 4; ++mi)
            af1[mi] = *(const shortx8*)
                &LA[(wm * 128 + (4 + mi) * 16 + lr) * 32 + lkk];
        __builtin_amdgcn_s_barrier();
        __builtin_amdgcn_s_setprio(1);
#pragma unroll
        for (int mi = 0; mi < 4; ++mi)
#pragma unroll
            for (int n = 0; n < 4; ++n)
                acc[4 + mi][n] = __builtin_amdgcn_mfma_f32_16x16x32_bf16(
                    af1[mi], bf[n], acc[4 + mi][n], 0, 0, 0);
        __builtin_amdgcn_s_setprio(0);

        // end-of-tile: tile t+1 must have landed; keep tile t+2's 4 loads in
        // flight (counted vmcnt, never 0 mid-loop; in-order retirement).
        if (pf)                   asm volatile("s_waitcnt vmcnt(4)" ::: "memory");
        else if (t + 1 < NT)      asm volatile("s_waitcnt vmcnt(0)" ::: "memory");
        __builtin_amdgcn_s_barrier();
        __builtin_amdgcn_sched_barrier(0);
        cur = (cur + 1 >= 3) ? 0 : cur + 1;
    }

    // ---- epilogue: val = relu(t1[i] + s_ij*c[j]), skip i==j, global sum.
    // C/D layout: col = lane&15, row = (lane>>4)*4 + reg  [m89-verified]
    const int row0 = arow0 + wm * 128 + (lane >> 4) * 4;
    const int col0 = brow0 + wn * 64 + lr;

    float local = 0.f;
#pragma unroll
    for (int n = 0; n < 4; ++n) {
        const int j = col0 + n * 16;
        const float cj = cc[j];
#pragma unroll
        for (int m = 0; m < 8; ++m) {
#pragma unroll
            for (int r = 0; r < 4; ++r) {
                const int i = row0 + m * 16 + r;
                float v = fmaxf(t1[i] + acc[m][n][r] * cj, 0.f);
                local += (i == j) ? 0.f : v;
            }
        }
    }

#pragma unroll
    for (int off = 32; off > 0; off >>= 1)
        local += __shfl_down(local, off);
    if (lane == 0) red[wid] = local;
    __syncthreads();
    if (tid == 0) {
        float s = 0.f;
#pragma unroll
        for (int w = 0; w < 8; ++w) s += red[w];
        atomicAdd(accum, s);
    }
}

// ---------------------------------------------------------------------------
// Kernel C: finalize -> float32 scalar
// ---------------------------------------------------------------------------
__global__ void finalize_kernel(const float* __restrict__ accum,
                                float* __restrict__ out)
{
    const float denom = 4096.0f * 4095.0f;  // exact in fp32
    out[0] = *accum / denom;
}

extern "C" void kernel_launch(void* const* d_in, const int* in_sizes, int n_in,
                              void* d_out, int out_size, void* d_ws, size_t ws_size,
                              hipStream_t stream) {
    const float* bnd   = (const float*)d_in[0];
    const float* proto = (const float*)d_in[1];
    const float* wgt   = (const float*)d_in[2];

    char* ws = (char*)d_ws;
    unsigned short* pbf = (unsigned short*)ws;                              // 16 MB
    unsigned short* wbf = (unsigned short*)(ws + (size_t)N_CLS * FDIM * 2); // 16 MB
    float* t1    = (float*)(ws + (size_t)N_CLS * FDIM * 4);
    float* cc    = t1 + N_CLS;
    float* accum = cc + N_CLS;

    zero_kernel<<<1, 1, 0, stream>>>(accum);
    prep_kernel<<<N_CLS, 256, 0, stream>>>(bnd, proto, wgt, pbf, wbf, t1, cc);
    gemm_reduce_kernel<<<256, 512, 0, stream>>>(pbf, wbf, t1, cc, accum);
    finalize_kernel<<<1, 1, 0, stream>>>(accum, (float*)d_out);
}

// Round 6
// 82.166 us; speedup vs baseline: 1.3857x; 1.3857x over previous
//
#include <hip/hip_runtime.h>
#include <hip/hip_bf16.h>

#define N_CLS 4096
#define FDIM  2048
#define ITERS 16          // 32 K-tiles of BK=64, 2 per iteration

typedef float  floatx4 __attribute__((ext_vector_type(4)));
typedef short  shortx8 __attribute__((ext_vector_type(8)));

__device__ __forceinline__ unsigned short f2bf(float x) {
    union { float f; unsigned int u; } v; v.f = x;
    unsigned int r = v.u + 0x7fffu + ((v.u >> 16) & 1u);
    return (unsigned short)(r >> 16);
}

__global__ void zero_kernel(float* __restrict__ accum) { *accum = 0.0f; }

// ---------------------------------------------------------------------------
// Kernel A: row norms, fp32 diag, bf16 conversion (HBM-roofline already).
// ---------------------------------------------------------------------------
__global__ __launch_bounds__(256) void prep_kernel(
    const float* __restrict__ bnd,
    const float* __restrict__ proto,
    const float* __restrict__ wgt,
    unsigned short* __restrict__ pbf,
    unsigned short* __restrict__ wbf,
    float* __restrict__ t1,
    float* __restrict__ cc)
{
    const int row = blockIdx.x;
    const int tid = threadIdx.x;
    const size_t base = (size_t)row * FDIM + (size_t)tid * 8;

    floatx4 p0 = *(const floatx4*)(proto + base);
    floatx4 p1 = *(const floatx4*)(proto + base + 4);
    floatx4 w0 = *(const floatx4*)(wgt + base);
    floatx4 w1 = *(const floatx4*)(wgt + base + 4);

    float ss = 0.f, dt = 0.f;
#pragma unroll
    for (int k = 0; k < 4; ++k) {
        ss += p0[k] * p0[k] + p1[k] * p1[k];
        dt += p0[k] * w0[k] + p1[k] * w1[k];
    }
#pragma unroll
    for (int off = 32; off > 0; off >>= 1) {
        ss += __shfl_down(ss, off);
        dt += __shfl_down(dt, off);
    }

    __shared__ float sss[4], sdt[4];
    __shared__ float srn;
    const int wid = tid >> 6, lane = tid & 63;
    if (lane == 0) { sss[wid] = ss; sdt[wid] = dt; }
    __syncthreads();
    if (tid == 0) {
        float SS = sss[0] + sss[1] + sss[2] + sss[3];
        float DT = sdt[0] + sdt[1] + sdt[2] + sdt[3];
        float rn = 1.0f / fmaxf(sqrtf(SS), 1e-12f);
        srn = rn;
        float bv = bnd[row];
        t1[row] = (1.0f - bv) * (DT * rn);
        cc[row] = bv - 1.0f;
    }
    __syncthreads();
    const float rn = srn;

    shortx8 pv, wv;
#pragma unroll
    for (int k = 0; k < 4; ++k) {
        pv[k]     = (short)f2bf(p0[k] * rn);
        pv[k + 4] = (short)f2bf(p1[k] * rn);
        wv[k]     = (short)f2bf(w0[k]);
        wv[k + 4] = (short)f2bf(w1[k]);
    }
    *(shortx8*)(pbf + base) = pv;
    *(shortx8*)(wbf + base) = wv;
}

// ---------------------------------------------------------------------------
// Kernel B: m201-style 8-phase GEMM + fused relu-sum epilogue.
// BM=BN=256, BK=64, 8 waves (2Mx4N), per-wave 128x64, acc[8][4] (16x16 frags).
// 2 x 64KB LDS dbuf; 4 half-tiles per K-tile (A0,A1,B0,B1 = 128rows x 64cols);
// one half staged per phase (2 x global_load_lds w16/thread); counted vmcnt
// schedule {8,12,10,-,8,12,10,-}; quadrant rotation so each half is ds_read
// in exactly one phase; B frags register-resident per tile.
// Swizzle both-sides: elem col ^= (row&7)<<3 (global pre-swizzle + ds_read).
// ---------------------------------------------------------------------------
#define PH_BAR() { __builtin_amdgcn_s_barrier(); __builtin_amdgcn_sched_barrier(0); }

#define RD_A(D, MH)                                                            \
    _Pragma("unroll") for (int mi = 0; mi < 4; ++mi) {                         \
        fa[mi][0] = *(const shortx8*)&sAB[D][aoff + (MH)*4096 + mi*1024 + cx0];\
        fa[mi][1] = *(const shortx8*)&sAB[D][aoff + (MH)*4096 + mi*1024 + cx1];\
    }
#define RD_B(D, NI0)                                                           \
    _Pragma("unroll") for (int ni = 0; ni < 2; ++ni) {                         \
        fb[(NI0)+ni][0] = *(const shortx8*)&sAB[D][boff + ((NI0)+ni)*1024 + cx0];\
        fb[(NI0)+ni][1] = *(const shortx8*)&sAB[D][boff + ((NI0)+ni)*1024 + cx1];\
    }
#define MFMA_Q(MI0, NI0)                                                       \
    __builtin_amdgcn_s_setprio(1);                                             \
    _Pragma("unroll") for (int kx = 0; kx < 2; ++kx)                           \
    _Pragma("unroll") for (int mi = 0; mi < 4; ++mi)                           \
    _Pragma("unroll") for (int ni = 0; ni < 2; ++ni)                           \
        acc[(MI0)+mi][(NI0)+ni] = __builtin_amdgcn_mfma_f32_16x16x32_bf16(     \
            fa[mi][kx], fb[(NI0)+ni][kx], acc[(MI0)+mi][(NI0)+ni], 0, 0, 0);   \
    __builtin_amdgcn_s_setprio(0);

__global__ __launch_bounds__(512, 2) void gemm_reduce_kernel(
    const unsigned short* __restrict__ A,   // p_bf16 [4096][2048]
    const unsigned short* __restrict__ B,   // w_bf16 [4096][2048]
    const float* __restrict__ t1,
    const float* __restrict__ cc,
    float* __restrict__ accum)
{
    __shared__ unsigned short sAB[2][32768];  // per buf: A0|A1|B0|B1, 8192 each
    __shared__ float red[8];

    const int tid  = threadIdx.x;
    const int wid  = tid >> 6;
    const int lane = tid & 63;

    // XCD-aware bijective swizzle: 256 blocks over 16x16 tile grid.
    const int b   = blockIdx.x;
    const int xcd = b & 7, sl = b >> 3;
    const int bi  = ((xcd & 3) << 2) + (sl & 3);
    const int bj  = ((xcd >> 2) << 3) + (sl >> 2);
    const int arow0 = bi * 256;
    const int brow0 = bj * 256;

    const int wm = wid >> 2;   // 0..1 : 128-row strip
    const int wn = wid & 3;    // 0..3 : 64-col strip
    const int lr = lane & 15;

    // swizzled frag-read col offsets (shorts) for kx=0/1:
    const int cx0 = (((lane >> 4)    ) ^ (lane & 7)) << 3;
    const int cx1 = ((4 | (lane >> 4)) ^ (lane & 7)) << 3;
    // frag base offsets (shorts) within a buffer:
    const int aoff = wm * 8192 + lr * 64;
    const int boff = 16384 + (wn >> 1) * 8192 + (wn & 1) * 4096 + lr * 64;

    // staging: thread t covers rows {t>>3, 64+(t>>3)} of a half, 8 elems each;
    // global col pre-swizzled so LDS[r][c] = G[r][c ^ ((r&7)<<3)].
    const int srow = tid >> 3;
    const int sgc  = (((tid & 7) ^ ((tid >> 3) & 7)) << 3);

    auto glds = [&](const unsigned short* src, unsigned short* dst) {
        __builtin_amdgcn_global_load_lds(
            (const __attribute__((address_space(1))) void*)src,
            (__attribute__((address_space(3))) void*)dst, 16, 0, 0);
    };
    auto stageA = [&](int h, int t) {
        unsigned short* dst = &sAB[t & 1][h * 8192 + tid * 8];
        const unsigned short* src =
            A + (size_t)(arow0 + h * 128 + srow) * FDIM + t * 64 + sgc;
        glds(src, dst);
        glds(src + (size_t)64 * FDIM, dst + 4096);
    };
    auto stageB = [&](int h, int t) {
        unsigned short* dst = &sAB[t & 1][16384 + h * 8192 + tid * 8];
        const unsigned short* src =
            B + (size_t)(brow0 + h * 128 + srow) * FDIM + t * 64 + sgc;
        glds(src, dst);
        glds(src + (size_t)64 * FDIM, dst + 4096);
    };

    floatx4 acc[8][4];
#pragma unroll
    for (int m = 0; m < 8; ++m)
#pragma unroll
        for (int n = 0; n < 4; ++n) acc[m][n] = (floatx4)0.0f;

    shortx8 fa[4][2];   // current A-half frags [mi][kx]
    shortx8 fb[4][2];   // B frags for current tile [ni][kx]

    // ---- prologue: 7 halves in steady-state issue order (14 loads in flight)
    stageB(0, 0); stageB(1, 0); stageA(0, 0); stageA(1, 0);
    stageB(0, 1); stageB(1, 1); stageA(0, 1);

#pragma unroll 1
    for (int i = 0; i < ITERS - 1; ++i) {
        const int c2 = 2 * i + 2, c3 = 2 * i + 3;
        // P0: tile c0 (buf0), quadrant (mh0, nh0)
        asm volatile("s_waitcnt vmcnt(8)" ::: "memory");
        PH_BAR();
        RD_A(0, 0); RD_B(0, 0);
        stageA(1, 2 * i + 1);
        MFMA_Q(0, 0);
        // P1: (mh0, nh1)
        asm volatile("s_waitcnt vmcnt(12)" ::: "memory");
        PH_BAR();
        RD_B(0, 2);
        stageB(0, c2);
        MFMA_Q(0, 2);
        // P2: (mh1, nh1)
        asm volatile("s_waitcnt vmcnt(10)" ::: "memory");
        PH_BAR();
        RD_A(0, 1);
        stageB(1, c2);
        MFMA_Q(4, 2);
        // P3: (mh1, nh0) — regs only
        PH_BAR();
        stageA(0, c2);
        MFMA_Q(4, 0);
        // P4: tile c1 (buf1), (mh0, nh0)
        asm volatile("s_waitcnt vmcnt(8)" ::: "memory");
        PH_BAR();
        RD_A(1, 0); RD_B(1, 0);
        stageA(1, c2);
        MFMA_Q(0, 0);
        // P5: (mh0, nh1)
        asm volatile("s_waitcnt vmcnt(12)" ::: "memory");
        PH_BAR();
        RD_B(1, 2);
        stageB(0, c3);
        MFMA_Q(0, 2);
        // P6: (mh1, nh1)
        asm volatile("s_waitcnt vmcnt(10)" ::: "memory");
        PH_BAR();
        RD_A(1, 1);
        stageB(1, c3);
        MFMA_Q(4, 2);
        // P7: (mh1, nh0)
        PH_BAR();
        stageA(0, c3);
        MFMA_Q(4, 0);
    }

    // ---- peeled tail (tiles 30, 31): no further stages except A1(31) at P0
    {
        asm volatile("s_waitcnt vmcnt(0)" ::: "memory");
        PH_BAR();
        RD_A(0, 0); RD_B(0, 0);
        stageA(1, 31);
        MFMA_Q(0, 0);
        PH_BAR();
        RD_B(0, 2);
        MFMA_Q(0, 2);
        PH_BAR();
        RD_A(0, 1);
        MFMA_Q(4, 2);
        PH_BAR();
        MFMA_Q(4, 0);
        PH_BAR();
        RD_A(1, 0); RD_B(1, 0);
        MFMA_Q(0, 0);
        PH_BAR();
        RD_B(1, 2);
        MFMA_Q(0, 2);
        asm volatile("s_waitcnt vmcnt(0)" ::: "memory");
        PH_BAR();
        RD_A(1, 1);
        MFMA_Q(4, 2);
        PH_BAR();
        MFMA_Q(4, 0);
    }

    // ---- epilogue: val = relu(t1[i] + s_ij*c[j]), skip i==j, global sum.
    // C/D layout: col = lane&15, row = (lane>>4)*4 + reg  [m89-verified]
    const int row0 = arow0 + wm * 128 + (lane >> 4) * 4;
    const int col0 = brow0 + wn * 64 + lr;

    float local = 0.f;
#pragma unroll
    for (int n = 0; n < 4; ++n) {
        const int j = col0 + n * 16;
        const float cj = cc[j];
#pragma unroll
        for (int m = 0; m < 8; ++m) {
#pragma unroll
            for (int r = 0; r < 4; ++r) {
                const int i = row0 + m * 16 + r;
                float v = fmaxf(t1[i] + acc[m][n][r] * cj, 0.f);
                local += (i == j) ? 0.f : v;
            }
        }
    }

#pragma unroll
    for (int off = 32; off > 0; off >>= 1)
        local += __shfl_down(local, off);
    if (lane == 0) red[wid] = local;
    __syncthreads();
    if (tid == 0) {
        float s = 0.f;
#pragma unroll
        for (int w = 0; w < 8; ++w) s += red[w];
        atomicAdd(accum, s);
    }
}

__global__ void finalize_kernel(const float* __restrict__ accum,
                                float* __restrict__ out)
{
    const float denom = 4096.0f * 4095.0f;  // exact in fp32
    out[0] = *accum / denom;
}

extern "C" void kernel_launch(void* const* d_in, const int* in_sizes, int n_in,
                              void* d_out, int out_size, void* d_ws, size_t ws_size,
                              hipStream_t stream) {
    const float* bnd   = (const float*)d_in[0];
    const float* proto = (const float*)d_in[1];
    const float* wgt   = (const float*)d_in[2];

    char* ws = (char*)d_ws;
    unsigned short* pbf = (unsigned short*)ws;                              // 16 MB
    unsigned short* wbf = (unsigned short*)(ws + (size_t)N_CLS * FDIM * 2); // 16 MB
    float* t1    = (float*)(ws + (size_t)N_CLS * FDIM * 4);
    float* cc    = t1 + N_CLS;
    float* accum = cc + N_CLS;

    zero_kernel<<<1, 1, 0, stream>>>(accum);
    prep_kernel<<<N_CLS, 256, 0, stream>>>(bnd, proto, wgt, pbf, wbf, t1, cc);
    gemm_reduce_kernel<<<256, 512, 0, stream>>>(pbf, wbf, t1, cc, accum);
    finalize_kernel<<<1, 1, 0, stream>>>(accum, (float*)d_out);
}